// Round 10
// baseline (792.368 us; speedup 1.0000x reference)
//
#include <hip/hip_runtime.h>
#include <hip/hip_bf16.h>

#define NN 100000
#define EE 500000
#define BB 4096
#define HC 128
#define SCAN_ELEM 1024
#define NSB ((NN + SCAN_ELEM - 1) / SCAN_ELEM)   // 98 blocks

typedef __bf16 bf16_t;
typedef bf16_t bf16x8 __attribute__((ext_vector_type(8)));
typedef float f32x4 __attribute__((ext_vector_type(4)));
typedef float f32x2 __attribute__((ext_vector_type(2)));

__device__ __forceinline__ unsigned short f2bf(float f) {
    unsigned u = __builtin_bit_cast(unsigned, f);
    u += 0x7FFFu + ((u >> 16) & 1u);            // RNE
    return (unsigned short)(u >> 16);
}
__device__ __forceinline__ float bflo(unsigned u) {   // low bf16 -> f32
    return __builtin_bit_cast(float, u << 16);
}
__device__ __forceinline__ float bfhi(unsigned u) {   // high bf16 -> f32
    return __builtin_bit_cast(float, u & 0xFFFF0000u);
}
__device__ __forceinline__ f32x2 unpk2(unsigned u) {  // packed pair -> 2 f32
    return (f32x2){ bflo(u), bfhi(u) };
}
// pack 2 f32 -> 2 bf16 in one instruction (RNE; bit-identical to f2bf pair).
// No builtin on gfx950 -> inline asm (cdna_hip_programming.md T12 recipe).
__device__ __forceinline__ unsigned pkbf(float lo, float hi) {
    unsigned r;
    asm volatile("v_cvt_pk_bf16_f32 %0, %1, %2" : "=v"(r) : "v"(lo), "v"(hi));
    return r;
}

// ---- convert+transpose ALL layers' weights in one dispatch ------------------
// Wt3 slots of 65536 us per layer: l0 (K=64) uses 32768; l1,l2 (K=128) 65536.
__global__ __launch_bounds__(256) void prep_w_all(
    const float* __restrict__ Wq1, const float* __restrict__ Wk1,
    const float* __restrict__ Wv1, const float* __restrict__ Ws1,
    const float* __restrict__ Wq23, const float* __restrict__ Wk23,
    const float* __restrict__ Wv23, const float* __restrict__ Ws23,
    unsigned short* __restrict__ Wt3)
{
    const int g = blockIdx.x * 256 + threadIdx.x;
    if (g >= 32768 + 131072) return;
    if (g < 32768) {                       // layer 0, K=64, per-plane 8192
        const int p = g >> 13, r = g & 8191;
        const int k = r >> 7, n = r & 127;
        const float* W = p == 0 ? Wq1 : p == 1 ? Wk1 : p == 2 ? Wv1 : Ws1;
        Wt3[p * 8192 + n * 64 + k] = f2bf(W[k * 128 + n]);
    } else {
        const int g2 = g - 32768;          // layers 1,2: K=128, per-plane 16384
        const int j = g2 >> 16;
        const int r3 = g2 & 65535;
        const int p = r3 >> 14, r = r3 & 16383;
        const int k = r >> 7, n = r & 127;
        const float* W = (p == 0 ? Wq23 : p == 1 ? Wk23 : p == 2 ? Wv23 : Ws23)
                       + (size_t)j * 128 * 128;
        Wt3[65536 + j * 65536 + p * 16384 + n * 128 + k] = f2bf(W[k * 128 + n]);
    }
}

// ---- MFMA GEMM: block = 4 waves = 4 planes, 32-row tile, 128 cols ----------
// ALL outputs packed bf16 (pair per dword), merged planes:
//   QSb[node] = [ Q : 64 dwords | S(skip) : 64 dwords ]   (stride 128)
//   KVb[node] = [ K : 64 dwords | V       : 64 dwords ]   (stride 128)
// Epilogue: v_cvt_pk_bf16_f32 (1 instr per pair) + NONTEMPORAL stores
// (consumer is cross-kernel/cross-XCD; NT drains writeback in THIS window
// instead of contending with the edge kernel's gathers).
// F32A=1: A is fp32 (layer-1 x), converted to bf16 fragments via cvt_pk.
template<int NKT, int F32A>
__global__ __launch_bounds__(256) void gemm_mfma(
    const unsigned short* __restrict__ Abf,
    const float* __restrict__ xf,
    const unsigned short* __restrict__ Wt,
    const float* __restrict__ bq, const float* __restrict__ bk,
    const float* __restrict__ bv, const float* __restrict__ bs,
    unsigned* __restrict__ QSb, unsigned* __restrict__ KVb)
{
    constexpr int K = NKT * 32;
    const int lane = threadIdx.x & 63;
    const int p = threadIdx.x >> 6;              // wave == plane
    const int m = lane & 15, kq = lane >> 4;
    const int rows0 = blockIdx.x * 32;

    const unsigned short* Wp = Wt + (size_t)p * 128 * K;
    const float* bias = p == 0 ? bq : p == 1 ? bk : p == 2 ? bv : bs;

    bf16x8 a[2][NKT];
#pragma unroll
    for (int mt = 0; mt < 2; mt++)
#pragma unroll
        for (int kt = 0; kt < NKT; kt++) {
            if constexpr (F32A) {
                const float* pr = xf + (size_t)(rows0 + mt * 16 + m) * K + kt * 32 + kq * 8;
                const float4 f0 = *(const float4*)pr;
                const float4 f1 = *(const float4*)(pr + 4);
                union { bf16x8 v; unsigned u[4]; } cv;
                cv.u[0] = pkbf(f0.x, f0.y);
                cv.u[1] = pkbf(f0.z, f0.w);
                cv.u[2] = pkbf(f1.x, f1.y);
                cv.u[3] = pkbf(f1.z, f1.w);
                a[mt][kt] = cv.v;
            } else {
                a[mt][kt] = *(const bf16x8*)(Abf + (size_t)(rows0 + mt * 16 + m) * K + kt * 32 + kq * 8);
            }
        }

    f32x4 acc[2][8];
#pragma unroll
    for (int mt = 0; mt < 2; mt++)
#pragma unroll
        for (int nt = 0; nt < 8; nt++)
            acc[mt][nt] = (f32x4){0.f, 0.f, 0.f, 0.f};

#pragma unroll
    for (int nt = 0; nt < 8; nt++) {
#pragma unroll
        for (int kt = 0; kt < NKT; kt++) {
            const bf16x8 b = *(const bf16x8*)(Wp + (size_t)(nt * 16 + m) * K + kt * 32 + kq * 8);
            acc[0][nt] = __builtin_amdgcn_mfma_f32_16x16x32_bf16(a[0][kt], b, acc[0][nt], 0, 0, 0);
            acc[1][nt] = __builtin_amdgcn_mfma_f32_16x16x32_bf16(a[1][kt], b, acc[1][nt], 0, 0, 0);
        }
    }

    unsigned* out = p == 0 ? QSb : p == 1 ? KVb : p == 2 ? (KVb + 64) : (QSb + 64);
#pragma unroll
    for (int nt = 0; nt < 8; nt++) {
        const float bi = bias[nt * 16 + m];
#pragma unroll
        for (int mt = 0; mt < 2; mt++) {
#pragma unroll
            for (int r = 0; r < 4; r++) {
                const float v0 = acc[mt][nt][r] + bi;
                const float v1 = __shfl_xor(v0, 1);
                if (!(m & 1)) {
                    const unsigned pk = pkbf(v0, v1);
                    __builtin_nontemporal_store(pk,
                        &out[(size_t)(rows0 + mt * 16 + kq * 4 + r) * 128 + nt * 8 + (m >> 1)]);
                }
            }
        }
    }
}

// ---- CSR build: degree histogram -> hierarchical scan -> bucket scatter -----
__global__ __launch_bounds__(256) void deg_k(const int* __restrict__ ei, int* __restrict__ deg)
{
    const int e = blockIdx.x * 256 + threadIdx.x;
    if (e < EE) atomicAdd(&deg[ei[EE + e]], 1);
}

__global__ __launch_bounds__(256) void scan_part(const int* __restrict__ deg,
                                                 int* __restrict__ bsum)
{
    __shared__ int red[256];
    const int base = blockIdx.x * SCAN_ELEM + threadIdx.x * 4;
    int s = 0;
#pragma unroll
    for (int j = 0; j < 4; j++) { const int i = base + j; if (i < NN) s += deg[i]; }
    red[threadIdx.x] = s;
    __syncthreads();
    for (int st = 128; st > 0; st >>= 1) {
        if (threadIdx.x < st) red[threadIdx.x] += red[threadIdx.x + st];
        __syncthreads();
    }
    if (threadIdx.x == 0) bsum[blockIdx.x] = red[0];
}

__global__ __launch_bounds__(128) void scan_top(const int* __restrict__ bsum,
                                                int* __restrict__ boff)
{
    __shared__ int buf[128];
    const int v = (threadIdx.x < NSB) ? bsum[threadIdx.x] : 0;
    buf[threadIdx.x] = v;
    __syncthreads();
    for (int s = 1; s < 128; s <<= 1) {
        const int t = (threadIdx.x >= s) ? buf[threadIdx.x - s] : 0;
        __syncthreads();
        buf[threadIdx.x] += t;
        __syncthreads();
    }
    if (threadIdx.x < NSB) boff[threadIdx.x] = buf[threadIdx.x] - v;
}

// scan_final also folds the per-graph node count (cnt_k) -- same node domain.
__global__ __launch_bounds__(256) void scan_final(const int* __restrict__ deg,
                                                  const int* __restrict__ boff,
                                                  int* __restrict__ off,
                                                  int* __restrict__ cursor,
                                                  const int* __restrict__ batch,
                                                  float* __restrict__ cnt)
{
    __shared__ int tsum[256];
    const int base = blockIdx.x * SCAN_ELEM + threadIdx.x * 4;
    int vals[4];
    int s = 0;
#pragma unroll
    for (int j = 0; j < 4; j++) {
        const int i = base + j;
        vals[j] = (i < NN) ? deg[i] : 0;
        s += vals[j];
    }
    tsum[threadIdx.x] = s;
    __syncthreads();
    for (int st = 1; st < 256; st <<= 1) {
        const int t = (threadIdx.x >= st) ? tsum[threadIdx.x - st] : 0;
        __syncthreads();
        tsum[threadIdx.x] += t;
        __syncthreads();
    }
    int ex = boff[blockIdx.x] + tsum[threadIdx.x] - s;
#pragma unroll
    for (int j = 0; j < 4; j++) {
        const int i = base + j;
        if (i < NN) {
            off[i] = ex; cursor[i] = ex;
            atomicAdd(&cnt[batch[i]], 1.0f);
        }
        ex += vals[j];
    }
    if (blockIdx.x == NSB - 1 && threadIdx.x == 255)
        off[NN] = boff[blockIdx.x] + tsum[255];
}

// bucket: write src node id AND reordered edge_attr at CSR slot.
__global__ __launch_bounds__(256) void bucket_k(const int* __restrict__ ei,
                                                const float* __restrict__ ea,
                                                int* __restrict__ cursor,
                                                int* __restrict__ esrc,
                                                float4* __restrict__ eaf)
{
    const int e = blockIdx.x * 256 + threadIdx.x;
    if (e < EE) {
        const int d = ei[EE + e];
        const int p = atomicAdd(&cursor[d], 1);
        esrc[p] = ei[e];
        eaf[p] = *(const float4*)(ea + (size_t)e * 4);
    }
}

// ---- Fused edge stage (R5 structure, measured-best): one wave per node, ----
// 4 edges in flight. Lane = slot*16 + c8; slot in [0,4): edge slot; c8 in
// [0,16): 8 channels (one dwordx4 of packed bf16 at KVb[src]*128 + c8*4,
// V at +64 dwords). Skip bf16-packed at QSb[n]*128 + 64.
// Algebra (e = We.a linear): q.(K+e) = q.K + a.(We^T q); per-lane qep folds
// into the per-edge shuffle reduce; sum(alpha*(V+e)) = sum(alpha*V) +
// We.(sum(alpha*a)) with running s4.
// fuse_pool=0: out = relu(msg/den + skip) -> bf16 Hb (NT store; consumer is
// the next GEMM, cross-XCD). fuse_pool=1: atomicAdd into pooled[batch[n]].
__global__ __launch_bounds__(256) void edge_fused(
    const int* __restrict__ esrc, const float4* __restrict__ eaf,
    const float* __restrict__ We,
    const unsigned* __restrict__ QSb, const unsigned* __restrict__ KVb,
    const int* __restrict__ off,
    unsigned short* __restrict__ Hb,
    const int* __restrict__ batch, float* __restrict__ pooled,
    int fuse_pool)
{
    const int lane = threadIdx.x & 63;
    const int slot = lane >> 4;          // edge slot 0..3
    const int c8   = lane & 15;          // channel group: channels c8*8 .. +7
    const int cb   = c8 * 8;
    const int ceq  = cb + slot * 2;      // this lane's epilogue channel pair
    const int n = blockIdx.x * 4 + (threadIdx.x >> 6);

    const int beg = off[n], end = off[n + 1];

    // issue independent loads early: q row + bf16 skip pair
    const uint4 qv = *(const uint4*)(QSb + (size_t)n * 128 + c8 * 4);
    const unsigned sku = QSb[(size_t)n * 128 + 64 + c8 * 4 + slot];
    f32x2 q2[4];
    q2[0] = unpk2(qv.x); q2[1] = unpk2(qv.y);
    q2[2] = unpk2(qv.z); q2[3] = unpk2(qv.w);

    // per-lane qe partials over my 8 channels (reduced jointly with q.K)
    float qep[4];
#pragma unroll
    for (int d = 0; d < 4; d++) {
        const float4 wa = *(const float4*)(We + d * HC + cb);
        const float4 wb = *(const float4*)(We + d * HC + cb + 4);
        qep[d] = wa.x * q2[0].x + wa.y * q2[0].y + wa.z * q2[1].x + wa.w * q2[1].y
               + wb.x * q2[2].x + wb.y * q2[2].y + wb.z * q2[3].x + wb.w * q2[3].y;
    }

    f32x2 num2[4] = {(f32x2){0.f, 0.f}, (f32x2){0.f, 0.f},
                     (f32x2){0.f, 0.f}, (f32x2){0.f, 0.f}};
    f32x4 s4 = (f32x4){0.f, 0.f, 0.f, 0.f};
    float den = 0.f;

    if (beg < end) {
        const int e1 = end - 1;
        int p0 = beg + slot; if (p0 > e1) p0 = e1;
        int src = esrc[p0];
        float4 a4 = eaf[p0];
        for (int base = beg; base < end; base += 4) {
            const unsigned* kv = KVb + (size_t)src * 128 + c8 * 4;
            const uint4 ku = *(const uint4*)kv;
            const uint4 vu = *(const uint4*)(kv + 64);
            const float4 ac = a4;
            const bool act = (base + slot) < end;
            if (base + 4 < end) {                  // 1-ahead prefetch
                int pn = base + 4 + slot; if (pn > e1) pn = e1;
                src = esrc[pn]; a4 = eaf[pn];
            }
            f32x2 t2 = q2[0] * unpk2(ku.x);
            t2 += q2[1] * unpk2(ku.y);
            t2 += q2[2] * unpk2(ku.z);
            t2 += q2[3] * unpk2(ku.w);
            float tot = t2.x + t2.y
                      + ac.x * qep[0] + ac.y * qep[1] + ac.z * qep[2] + ac.w * qep[3];
            tot += __shfl_xor(tot, 1);            // 4-lane head group reduce
            tot += __shfl_xor(tot, 2);
            float al = __expf(tot * 0.17677669529663687f);   // 1/sqrt(32)
            if (!act) al = 0.f;
            num2[0] += unpk2(vu.x) * al;
            num2[1] += unpk2(vu.y) * al;
            num2[2] += unpk2(vu.z) * al;
            num2[3] += unpk2(vu.w) * al;
            s4.x += ac.x * al; s4.y += ac.y * al;
            s4.z += ac.z * al; s4.w += ac.w * al;
            den += al;
        }
    }

    // cross-slot combine (once per node)
#pragma unroll
    for (int j = 0; j < 4; j++) {
        num2[j].x += __shfl_xor(num2[j].x, 16);
        num2[j].y += __shfl_xor(num2[j].y, 16);
        num2[j].x += __shfl_xor(num2[j].x, 32);
        num2[j].y += __shfl_xor(num2[j].y, 32);
    }
    s4.x += __shfl_xor(s4.x, 16); s4.y += __shfl_xor(s4.y, 16);
    s4.z += __shfl_xor(s4.z, 16); s4.w += __shfl_xor(s4.w, 16);
    s4.x += __shfl_xor(s4.x, 32); s4.y += __shfl_xor(s4.y, 32);
    s4.z += __shfl_xor(s4.z, 32); s4.w += __shfl_xor(s4.w, 32);
    den += __shfl_xor(den, 16);
    den += __shfl_xor(den, 32);
    const float inv = 1.f / (den + 1e-16f);

    // my channel pair (static-index selection)
    f32x2 mynum = slot == 0 ? num2[0] : slot == 1 ? num2[1]
                : slot == 2 ? num2[2] : num2[3];
    // edge-attr contribution for my 2 channels: We . s4
    float ev0 = 0.f, ev1 = 0.f;
#pragma unroll
    for (int d = 0; d < 4; d++) {
        const float2 wd = *(const float2*)(We + d * HC + ceq);
        const float sd = d == 0 ? s4.x : d == 1 ? s4.y : d == 2 ? s4.z : s4.w;
        ev0 += sd * wd.x;
        ev1 += sd * wd.y;
    }
    const float o0 = (mynum.x + ev0) * inv + bflo(sku);
    const float o1 = (mynum.y + ev1) * inv + bfhi(sku);

    if (!fuse_pool) {
        const unsigned pk = pkbf(fmaxf(o0, 0.f), fmaxf(o1, 0.f));
        __builtin_nontemporal_store(pk, (unsigned*)(Hb + (size_t)n * HC + ceq));
    } else {
        const int b = batch[n];
        atomicAdd(pooled + (size_t)b * HC + ceq,     o0);
        atomicAdd(pooled + (size_t)b * HC + ceq + 1, o1);
    }
}

__global__ __launch_bounds__(256) void head_k(
    const float* __restrict__ pooled, const float* __restrict__ cnt,
    const int* __restrict__ rt, const float* __restrict__ hW,
    const float* __restrict__ hb, float* __restrict__ out)
{
    const int lane = threadIdx.x & 63;
    const int b = blockIdx.x * 4 + (threadIdx.x >> 6);
    if (b >= BB) return;
    const int t = rt[b];
    const int c = lane * 2;
    const float2 p2 = *(const float2*)(pooled + (size_t)b * HC + c);
    const float2 w2 = *(const float2*)(hW + (size_t)t * HC + c);
    float part = p2.x * w2.x + p2.y * w2.y;
    part += __shfl_xor(part, 1);
    part += __shfl_xor(part, 2);
    part += __shfl_xor(part, 4);
    part += __shfl_xor(part, 8);
    part += __shfl_xor(part, 16);
    part += __shfl_xor(part, 32);
    if (lane == 0) out[b] = part / fmaxf(cnt[b], 1.0f) + hb[t];
}

extern "C" void kernel_launch(void* const* d_in, const int* in_sizes, int n_in,
                              void* d_out, int out_size, void* d_ws, size_t ws_size,
                              hipStream_t stream) {
    const float* x      = (const float*)d_in[0];
    const int*   ei     = (const int*)d_in[1];
    const float* ea     = (const float*)d_in[2];
    const int*   batch  = (const int*)d_in[3];
    const int*   rt     = (const int*)d_in[4];

    // workspace layout — big 16B-aligned arrays first; ~141 MB total.
    // pooled|cnt|deg are adjacent -> ONE memset covers all three.
    unsigned* QSb = (unsigned*)d_ws;                      // 12,800,000 u32 (Q|S bf16)
    unsigned* KVb = QSb + 12800000;                       // 12,800,000 u32 (K|V bf16)
    unsigned short* Abf = (unsigned short*)(KVb + 12800000); // 12,800,000 us (h plane)
    float4* eaf   = (float4*)(Abf + 12800000);            // 500,000 float4
    unsigned short* Wt3 = (unsigned short*)(eaf + 500000);// 196,608 us (3 x 65536)
    float* pooled = (float*)(Wt3 + 196608);               // 524,288 f
    float* cnt    = pooled + 524288;                      // 4,096 f
    int*   deg    = (int*)(cnt + 4096);                   // 100,000 i
    int*   esrc   = deg + 100000;                         // 500,000 i
    int*   off    = esrc + 500000;                        // 100,001 i (+pad)
    int*   cursor = off + 100004;                         // 100,000 i
    int*   bsum   = cursor + 100000;                      // 128 i
    int*   boff   = bsum + 128;                           // 128 i

    // ---- single merged zero-fill (pooled + cnt + deg contiguous)
    hipMemsetAsync(pooled, 0, (size_t)(524288 + 4096 + 100000) * sizeof(float), stream);

    // ---- CSR build (graph identical every call; ws re-poisoned each call)
    deg_k<<<(EE + 255) / 256, 256, 0, stream>>>(ei, deg);
    scan_part<<<NSB, 256, 0, stream>>>(deg, bsum);
    scan_top<<<1, 128, 0, stream>>>(bsum, boff);
    scan_final<<<NSB, 256, 0, stream>>>(deg, boff, off, cursor, batch, cnt);
    bucket_k<<<(EE + 255) / 256, 256, 0, stream>>>(ei, ea, cursor, esrc, eaf);

    // ---- all weight planes in one dispatch
    prep_w_all<<<640, 256, 0, stream>>>(
        (const float*)d_in[5], (const float*)d_in[7], (const float*)d_in[9],
        (const float*)d_in[12],
        (const float*)d_in[14], (const float*)d_in[16], (const float*)d_in[18],
        (const float*)d_in[21], Wt3);

    for (int l = 0; l < 3; l++) {
        const float *bq, *bk, *bv, *bs, *We;
        if (l == 0) {
            bq = (const float*)d_in[6];  bk = (const float*)d_in[8];
            bv = (const float*)d_in[10]; bs = (const float*)d_in[13];
            We = (const float*)d_in[11];
        } else {
            const int j = l - 1;
            bq = (const float*)d_in[15] + j * HC;
            bk = (const float*)d_in[17] + j * HC;
            bv = (const float*)d_in[19] + j * HC;
            bs = (const float*)d_in[22] + j * HC;
            We = (const float*)d_in[20] + (size_t)j * 4 * HC;
        }
        const unsigned short* Wt = Wt3 + (size_t)l * 65536;

        if (l == 0)
            gemm_mfma<2, 1><<<NN / 32, 256, 0, stream>>>(Abf, x, Wt, bq, bk, bv, bs, QSb, KVb);
        else
            gemm_mfma<4, 0><<<NN / 32, 256, 0, stream>>>(Abf, x, Wt, bq, bk, bv, bs, QSb, KVb);
        edge_fused<<<NN / 4, 256, 0, stream>>>(esrc, eaf, We, QSb, KVb, off,
                                               Abf, batch, pooled,
                                               l == 2 ? 1 : 0);
    }

    head_k<<<BB / 4, 256, 0, stream>>>(pooled, cnt, rt,
        (const float*)d_in[23], (const float*)d_in[24], (float*)d_out);
}